// Round 1
// 3186.408 us; speedup vs baseline: 2.6216x; 2.6216x over previous
//
#include <hip/hip_runtime.h>
#include <math.h>

#define B_  16
#define T_  128
#define N_  50
#define D_  512
#define KH  8
#define DH  64

typedef unsigned short u16;
typedef unsigned int   u32;

using bf16x8 = __attribute__((ext_vector_type(8))) __bf16;
using f32x4  = __attribute__((ext_vector_type(4))) float;

__device__ __forceinline__ f32x4 mfma_bf16(uint4 a, uint4 b, f32x4 c) {
    return __builtin_amdgcn_mfma_f32_16x16x32_bf16(
        __builtin_bit_cast(bf16x8, a),
        __builtin_bit_cast(bf16x8, b), c, 0, 0, 0);
}

// split two fp32 into packed bf16 hi-plane word and lo-plane word
//   hi = truncate-to-bf16(x); lo = bf16(x - hi)  (x - hi exact in fp32)
__device__ __forceinline__ void split2(float a, float b, u32& h, u32& l) {
    u32 au = __float_as_uint(a), bu = __float_as_uint(b);
    u32 ah = au & 0xFFFF0000u,  bh = bu & 0xFFFF0000u;
    h = (au >> 16) | bh;
    float la = a - __uint_as_float(ah);
    float lb = b - __uint_as_float(bh);
    l = (__float_as_uint(la) >> 16) | (__float_as_uint(lb) & 0xFFFF0000u);
}

__device__ __forceinline__ void split8(float4 f0, float4 f1, uint4& h, uint4& l) {
    split2(f0.x, f0.y, h.x, l.x);
    split2(f0.z, f0.w, h.y, l.y);
    split2(f1.x, f1.y, h.z, l.z);
    split2(f1.z, f1.w, h.w, l.w);
}

// ---------------------------------------------------------------------------
// Weight pre-transform: W (K x 512, fp32, row-major) -> Wt_hi/Wt_lo
// (512 x K, bf16 planes). Output-centric: each thread writes 8 consecutive k
// for one n (coalesced 16B stores); strided reads are L2-cached (W <= 3MB).
// ---------------------------------------------------------------------------
__global__ __launch_bounds__(256) void wsplit_kernel(
    const float* __restrict__ W, u16* __restrict__ th, u16* __restrict__ tl, int K)
{
    const int idx  = blockIdx.x * 256 + threadIdx.x;
    const int kper = K >> 3;
    const int n    = idx / kper;
    const int kb   = (idx - n * kper) * 8;
    float x0 = W[(size_t)(kb + 0) * 512 + n];
    float x1 = W[(size_t)(kb + 1) * 512 + n];
    float x2 = W[(size_t)(kb + 2) * 512 + n];
    float x3 = W[(size_t)(kb + 3) * 512 + n];
    float x4 = W[(size_t)(kb + 4) * 512 + n];
    float x5 = W[(size_t)(kb + 5) * 512 + n];
    float x6 = W[(size_t)(kb + 6) * 512 + n];
    float x7 = W[(size_t)(kb + 7) * 512 + n];
    uint4 h, l;
    split2(x0, x1, h.x, l.x);
    split2(x2, x3, h.y, l.y);
    split2(x4, x5, h.z, l.z);
    split2(x6, x7, h.w, l.w);
    *(uint4*)&th[(size_t)n * K + kb] = h;
    *(uint4*)&tl[(size_t)n * K + kb] = l;
}

// ---------------------------------------------------------------------------
// Split-bf16 MFMA GEMM: C = act(A @ W + bias), output width fixed at 512.
//   a_mode==0: A plain (M x K fp32);  a_mode==1: A = concat(X[512], TLE[1024])
//   Wth/Wtl: pre-split transposed weights (512 x K bf16 planes).
//   Tile 128x128, BK=32, 256 threads = 4 waves, each wave owns 64x64
//   (4x4 fragments of 16x16), 3 MFMAs per fragment (hi*hi + hi*lo + lo*hi).
// LDS rows padded to 40 u16 (80B) -> frag b128 reads are 2-way (free).
// ---------------------------------------------------------------------------
__global__ __launch_bounds__(256, 2) void mgemm_kernel(
    const float* __restrict__ A,
    const float* __restrict__ X,
    const float* __restrict__ TLE,
    const u16* __restrict__ Wth,
    const u16* __restrict__ Wtl,
    const float* __restrict__ bias,
    float* __restrict__ C,
    int K, int do_relu, int a_mode)
{
    __shared__ __align__(16) u16 As_hi[128][40];
    __shared__ __align__(16) u16 As_lo[128][40];
    __shared__ __align__(16) u16 Bs_hi[128][40];
    __shared__ __align__(16) u16 Bs_lo[128][40];

    const int tid  = threadIdx.x;
    const int lane = tid & 63;
    const int wave = tid >> 6;
    const int wm   = (wave >> 1) * 64;
    const int wn   = (wave & 1) * 64;
    const int fr   = lane & 15;      // fragment row (A) / col (B/D)
    const int ks   = lane >> 4;      // k-subgroup (0..3), 8 elements each

    // XCD-aware swizzle: put the 4 n-blocks of one m-panel on one XCD's L2.
    // Bijective only when gridDim.y % 8 == 0; identity otherwise.
    int m_idx, n_idx;
    {
        const int bid = blockIdx.y * 4 + blockIdx.x;
        if ((gridDim.y & 7) == 0) {
            m_idx = (bid >> 5) * 8 + (bid & 7);
            n_idx = (bid >> 3) & 3;
        } else {
            m_idx = blockIdx.y;
            n_idx = blockIdx.x;
        }
    }
    const int n0 = n_idx * 128;
    const int m0 = m_idx * 128;

    // staging: thread t loads 16 fp32 of A (row t>>1, k-half (t&1)*16) and
    // 16 bf16 per plane of B (col-row t>>1, same k-half)
    const int s_row = tid >> 1;
    const int s_kh  = (tid & 1) << 4;

    f32x4 acc[4][4];
    const f32x4 zero = {0.f, 0.f, 0.f, 0.f};
    #pragma unroll
    for (int i = 0; i < 4; ++i)
        #pragma unroll
        for (int j = 0; j < 4; ++j)
            acc[i][j] = zero;

    const float* a_row0 = (a_mode == 0) ? (A + (size_t)(m0 + s_row) * K) : nullptr;
    const float* x_row  = (a_mode == 1) ? (X   + (size_t)(m0 + s_row) * 512)  : nullptr;
    const float* t_row  = (a_mode == 1) ? (TLE + (size_t)(m0 + s_row) * 1024) : nullptr;
    const u16* bh_row = Wth + (size_t)(n0 + s_row) * K;
    const u16* bl_row = Wtl + (size_t)(n0 + s_row) * K;

    for (int k0 = 0; k0 < K; k0 += 32) {
        const int kk0 = k0 + s_kh;
        // ---- global loads (issued before barrier: overlap prev MFMAs) ----
        const float* asrc = (a_mode == 0) ? (a_row0 + kk0)
                          : (kk0 < 512 ? x_row + kk0 : t_row + (kk0 - 512));
        float4 f0 = ((const float4*)asrc)[0];
        float4 f1 = ((const float4*)asrc)[1];
        float4 f2 = ((const float4*)asrc)[2];
        float4 f3 = ((const float4*)asrc)[3];
        uint4 bh0 = *(const uint4*)(bh_row + kk0);
        uint4 bh1 = *(const uint4*)(bh_row + kk0 + 8);
        uint4 bl0 = *(const uint4*)(bl_row + kk0);
        uint4 bl1 = *(const uint4*)(bl_row + kk0 + 8);

        uint4 ah0, al0, ah1, al1;
        split8(f0, f1, ah0, al0);
        split8(f2, f3, ah1, al1);

        __syncthreads();   // previous tile's fragment reads are done
        *(uint4*)&As_hi[s_row][s_kh]     = ah0;
        *(uint4*)&As_hi[s_row][s_kh + 8] = ah1;
        *(uint4*)&As_lo[s_row][s_kh]     = al0;
        *(uint4*)&As_lo[s_row][s_kh + 8] = al1;
        *(uint4*)&Bs_hi[s_row][s_kh]     = bh0;
        *(uint4*)&Bs_hi[s_row][s_kh + 8] = bh1;
        *(uint4*)&Bs_lo[s_row][s_kh]     = bl0;
        *(uint4*)&Bs_lo[s_row][s_kh + 8] = bl1;
        __syncthreads();

        // ---- fragment reads (b128, 2-way bank alias max) ----
        uint4 fa_h[4], fa_l[4], fb_h[4], fb_l[4];
        #pragma unroll
        for (int i = 0; i < 4; ++i) {
            fa_h[i] = *(const uint4*)&As_hi[wm + i * 16 + fr][ks << 3];
            fa_l[i] = *(const uint4*)&As_lo[wm + i * 16 + fr][ks << 3];
            fb_h[i] = *(const uint4*)&Bs_hi[wn + i * 16 + fr][ks << 3];
            fb_l[i] = *(const uint4*)&Bs_lo[wn + i * 16 + fr][ks << 3];
        }

        // ---- 3-product split MFMAs ----
        #pragma unroll
        for (int mi = 0; mi < 4; ++mi)
            #pragma unroll
            for (int ni = 0; ni < 4; ++ni) {
                acc[mi][ni] = mfma_bf16(fa_h[mi], fb_h[ni], acc[mi][ni]);
                acc[mi][ni] = mfma_bf16(fa_h[mi], fb_l[ni], acc[mi][ni]);
                acc[mi][ni] = mfma_bf16(fa_l[mi], fb_h[ni], acc[mi][ni]);
            }
    }

    // ---- epilogue: D layout col = lane&15, row = (lane>>4)*4 + reg ----
    #pragma unroll
    for (int ni = 0; ni < 4; ++ni) {
        const int col = n0 + wn + ni * 16 + fr;
        const float bb = bias[col];
        #pragma unroll
        for (int mi = 0; mi < 4; ++mi) {
            const int row = m0 + wm + mi * 16 + (ks << 2);
            float* cp = C + (size_t)row * 512 + col;
            #pragma unroll
            for (int r = 0; r < 4; ++r) {
                float v = acc[mi][ni][r] + bb;
                if (do_relu) v = fmaxf(v, 0.f);
                cp[(size_t)r * 512] = v;
            }
        }
    }
}

// ---------------------------------------------------------------------------
// Attention (unchanged): one block per (b_local, n, h). 128 threads, one per
// query row. Two-pass softmax; k/v tiles staged in LDS. In-place over q.
// ---------------------------------------------------------------------------
__global__ __launch_bounds__(128) void attn_kernel(
    float* __restrict__ q,
    const float* __restrict__ k,
    const float* __restrict__ v,
    const int* __restrict__ kpm)
{
    __shared__ __align__(16) float ks[T_ * DH];   // 32 KB
    __shared__ __align__(16) float vs[T_ * DH];   // 32 KB

    const int h = blockIdx.x;
    const int n = blockIdx.y;
    const int b = blockIdx.z;
    const int tid = threadIdx.x;

    const size_t tstride = (size_t)N_ * D_;
    const size_t base = ((size_t)b * T_ * N_ + n) * D_ + (size_t)h * DH;

    for (int idx = tid; idx < T_ * (DH / 4); idx += 128) {
        const int row = idx >> 4;
        const int d4  = (idx & 15) * 4;
        *(float4*)&ks[row * DH + d4] = *(const float4*)(k + base + row * tstride + d4);
        *(float4*)&vs[row * DH + d4] = *(const float4*)(v + base + row * tstride + d4);
    }

    const int t = tid;
    float qr[DH];
    {
        const float* qp = q + base + t * tstride;
        #pragma unroll
        for (int d4 = 0; d4 < DH; d4 += 4)
            *(float4*)&qr[d4] = *(const float4*)(qp + d4);
    }
    __syncthreads();

    const int L    = kpm[b];
    const int pmax = min(t + 1, L);

    float m = -1e30f;
    for (int p = 0; p < pmax; ++p) {
        const float* kp = &ks[p * DH];
        float acc = 0.f;
        #pragma unroll
        for (int d = 0; d < DH; ++d) acc = fmaf(qr[d], kp[d], acc);
        m = fmaxf(m, acc * 0.125f);
    }

    float out[DH];
    #pragma unroll
    for (int d = 0; d < DH; ++d) out[d] = 0.f;
    float sum = 0.f;
    for (int p = 0; p < pmax; ++p) {
        const float* kp = &ks[p * DH];
        float acc = 0.f;
        #pragma unroll
        for (int d = 0; d < DH; ++d) acc = fmaf(qr[d], kp[d], acc);
        const float e = __expf(acc * 0.125f - m);
        sum += e;
        const float* vp = &vs[p * DH];
        #pragma unroll
        for (int d = 0; d < DH; ++d) out[d] = fmaf(e, vp[d], out[d]);
    }
    const float inv = 1.0f / sum;

    float* op = q + base + t * tstride;
    #pragma unroll
    for (int d4 = 0; d4 < DH; d4 += 4) {
        float4 o = make_float4(out[d4] * inv, out[d4+1] * inv,
                               out[d4+2] * inv, out[d4+3] * inv);
        *(float4*)(op + d4) = o;
    }
}

// ---------------------------------------------------------------------------
// Host
// ---------------------------------------------------------------------------
extern "C" void kernel_launch(void* const* d_in, const int* in_sizes, int n_in,
                              void* d_out, int out_size, void* d_ws, size_t ws_size,
                              hipStream_t stream)
{
    const float* X   = (const float*)d_in[0];
    const float* TLE = (const float*)d_in[1];
    const int*   kpm = (const int*)  d_in[2];
    const float* Wq  = (const float*)d_in[3];
    const float* bq  = (const float*)d_in[4];
    const float* Wk  = (const float*)d_in[5];
    const float* bk  = (const float*)d_in[6];
    const float* Wv  = (const float*)d_in[7];
    const float* bv  = (const float*)d_in[8];
    const float* W1  = (const float*)d_in[9];
    const float* b1  = (const float*)d_in[10];
    const float* W2  = (const float*)d_in[11];
    const float* b2  = (const float*)d_in[12];
    float* out = (float*)d_out;

    // workspace layout: split weights first, then fp32 q/k/v scratch
    const size_t WQE = (size_t)512 * 1536;   // elements per QKV plane
    const size_t WFE = (size_t)512 * 512;    // elements per FFN plane
    u16* p = (u16*)d_ws;
    u16* wq_hi = p; p += WQE;  u16* wq_lo = p; p += WQE;
    u16* wk_hi = p; p += WQE;  u16* wk_lo = p; p += WQE;
    u16* wv_hi = p; p += WQE;  u16* wv_lo = p; p += WQE;
    u16* w1_hi = p; p += WFE;  u16* w1_lo = p; p += WFE;
    u16* w2_hi = p; p += WFE;  u16* w2_lo = p; p += WFE;
    const size_t wt_bytes =
        (((size_t)(6 * WQE + 4 * WFE) * sizeof(u16)) + 255) & ~(size_t)255;

    // weight transpose+split (once per launch; ~12 MB total)
    wsplit_kernel<<<dim3(512 * (1536 / 8) / 256), 256, 0, stream>>>(Wq, wq_hi, wq_lo, 1536);
    wsplit_kernel<<<dim3(512 * (1536 / 8) / 256), 256, 0, stream>>>(Wk, wk_hi, wk_lo, 1536);
    wsplit_kernel<<<dim3(512 * (1536 / 8) / 256), 256, 0, stream>>>(Wv, wv_hi, wv_lo, 1536);
    wsplit_kernel<<<dim3(512 * (512  / 8) / 256), 256, 0, stream>>>(W1, w1_hi, w1_lo, 512);
    wsplit_kernel<<<dim3(512 * (512  / 8) / 256), 256, 0, stream>>>(W2, w2_hi, w2_lo, 512);

    // pick largest chunk_B whose fp32 scratch fits after the weight area
    int chunk_B = 16;
    while (chunk_B > 1 &&
           wt_bytes + (size_t)3 * chunk_B * T_ * N_ * D_ * sizeof(float) > ws_size)
        chunk_B >>= 1;

    const size_t rows_per_b = (size_t)T_ * N_;   // 6400
    float* fbase = (float*)((char*)d_ws + wt_bytes);

    for (int b0 = 0; b0 < B_; b0 += chunk_B) {
        const int cb = chunk_B;
        const size_t row0  = (size_t)b0 * rows_per_b;
        const size_t crows = (size_t)cb * rows_per_b;
        const size_t bufsz = crows * D_;

        float* qb = fbase;
        float* kb = qb + bufsz;
        float* vb = kb + bufsz;

        const dim3 ggrid(4, (unsigned)(crows / 128));
        const float* Xc   = X   + row0 * 512;
        const float* TLEc = TLE + row0 * 1024;

        // QKV projections: relu(concat(X,TLE) @ W + b)
        mgemm_kernel<<<ggrid, 256, 0, stream>>>(nullptr, Xc, TLEc, wq_hi, wq_lo, bq, qb, 1536, 1, 1);
        mgemm_kernel<<<ggrid, 256, 0, stream>>>(nullptr, Xc, TLEc, wk_hi, wk_lo, bk, kb, 1536, 1, 1);
        mgemm_kernel<<<ggrid, 256, 0, stream>>>(nullptr, Xc, TLEc, wv_hi, wv_lo, bv, vb, 1536, 1, 1);

        // attention (in-place over qb)
        attn_kernel<<<dim3(KH, N_, cb), dim3(128), 0, stream>>>(qb, kb, vb, kpm + b0);

        // FFN
        mgemm_kernel<<<ggrid, 256, 0, stream>>>(qb, nullptr, nullptr, w1_hi, w1_lo, b1, kb, 512, 1, 0);
        mgemm_kernel<<<ggrid, 256, 0, stream>>>(kb, nullptr, nullptr, w2_hi, w2_lo, b2,
                                                out + row0 * D_, 512, 0, 0);
    }
}